// Round 9
// baseline (3678.572 us; speedup 1.0000x reference)
//
#include <hip/hip_runtime.h>
#include <math.h>

// Problem dims
#define Sn 128
#define Bn 16
#define Hn 1024
#define En 512
#define Vn 32000
#define H3 3072
#define NL0 32
#define NL1 64

typedef _Float16 h16;
typedef __attribute__((ext_vector_type(4))) _Float16 h16x4;
typedef __attribute__((ext_vector_type(8))) _Float16 h16x8;
typedef __attribute__((ext_vector_type(4))) float f32x4;
typedef unsigned long long u64;

// ---------- fused f32 -> fp16 convert for ALL operands (one launch) ----------
#define Q_EMB   4096000
#define Q_WIH0  (Q_EMB + 393216)
#define Q_W1    (Q_WIH0 + 262144)
#define Q_W2    (Q_W1 + 131072)
#define Q_WHH0  (Q_W2 + 786432)
#define Q_WIH1  (Q_WHH0 + 786432)
#define Q_WHH1  (Q_WIH1 + 786432)
#define Q_HID   (Q_WHH1 + 8192)
__global__ __launch_bounds__(256) void cvt_all_k(
    const float* __restrict__ emb, const float* __restrict__ wih0,
    const float* __restrict__ w1, const float* __restrict__ w2,
    const float* __restrict__ whh0, const float* __restrict__ wih1,
    const float* __restrict__ whh1, const float* __restrict__ hid,
    h16* __restrict__ E, h16* __restrict__ A, h16* __restrict__ B1,
    h16* __restrict__ B2, h16* __restrict__ D0, h16* __restrict__ D1,
    h16* __restrict__ D2, h16* __restrict__ HD)
{
  int i = blockIdx.x * 256 + threadIdx.x;
  const float* s; h16* d; int o;
  if      (i < Q_EMB)  { s = emb;  d = E;  o = i; }
  else if (i < Q_WIH0) { s = wih0; d = A;  o = i - Q_EMB; }
  else if (i < Q_W1)   { s = w1;   d = B1; o = i - Q_WIH0; }
  else if (i < Q_W2)   { s = w2;   d = B2; o = i - Q_W1; }
  else if (i < Q_WHH0) { s = whh0; d = D0; o = i - Q_W2; }
  else if (i < Q_WIH1) { s = wih1; d = D1; o = i - Q_WHH0; }
  else if (i < Q_WHH1) { s = whh1; d = D2; o = i - Q_WIH1; }
  else                 { s = hid;  d = HD; o = i - Q_WHH1; }
  float4 v = *(const float4*)(s + (size_t)o * 4);
  h16x4 ov = { (h16)v.x, (h16)v.y, (h16)v.z, (h16)v.w };
  *(h16x4*)(d + (size_t)o * 4) = ov;
}

// ---------- embedding gather -> fp16 X, time-major rows t = s*Bn + b ----------
__global__ void embed_k(const int* __restrict__ trg, const float* __restrict__ emb,
                        h16* __restrict__ Xh) {
  int t = blockIdx.x;
  int s = t >> 4, b = t & 15;
  int tok = trg[b * Sn + s];
  const float* src = emb + (size_t)tok * En;
  int e = threadIdx.x * 4;
  float4 v = *(const float4*)(src + e);
  h16x4 o = { (h16)v.x, (h16)v.y, (h16)v.z, (h16)v.w };
  *(h16x4*)(Xh + (size_t)t * En + e) = o;
}

// ---------- fp16 MFMA GEMM 128x128: C(M,N) = A(M,K) @ B(N,K)^T + bias ----------
template<int OUT_MODE, bool RELU, bool SWZ>
__global__ __launch_bounds__(256) void gemm_bt(
    const h16* __restrict__ A, const h16* __restrict__ B,
    const float* __restrict__ bias, void* __restrict__ C,
    int M, int N, int K)
{
  __shared__ h16 As[128 * 64];
  __shared__ h16 Bs[128 * 64];
  int tid = threadIdx.x;
  int l = tid & 63, wv = tid >> 6;
  int wr = wv >> 1, wc = wv & 1;

  int work = blockIdx.x;
  if (SWZ) { int q = gridDim.x >> 3; work = (work & 7) * q + (work >> 3); }
  int nMp = M >> 7;
  int brow = (work % nMp) << 7;
  int bcol = (work / nMp) << 7;

  f32x4 acc[4][4];
#pragma unroll
  for (int m = 0; m < 4; ++m)
#pragma unroll
    for (int n = 0; n < 4; ++n) acc[m][n] = (f32x4){0.f, 0.f, 0.f, 0.f};

  int nkt = K >> 6;
  for (int kt = 0; kt < nkt; ++kt) {
    const h16* Ag = A + (size_t)brow * K + kt * 64;
    const h16* Bg = B + (size_t)bcol * K + kt * 64;
#pragma unroll
    for (int c = tid; c < 2048; c += 256) {
      int half = c >> 10;
      int cc = c & 1023;
      int row = cc >> 3, slot = cc & 7;
      const h16* src = (half ? Bg : Ag) + (size_t)row * K + slot * 8;
      uint4 v = *(const uint4*)src;
      h16* dst = (half ? Bs : As) + row * 64 + ((slot ^ (row & 7)) << 3);
      *(uint4*)dst = v;
    }
    __syncthreads();
#pragma unroll
    for (int kk = 0; kk < 2; ++kk) {
      h16x8 af[4], bfr[4];
      int rb = wr * 64 + (l & 15);
      int cb2 = wc * 64 + (l & 15);
      int slot = kk * 4 + (l >> 4);
#pragma unroll
      for (int m = 0; m < 4; ++m) {
        int r = rb + m * 16;
        af[m] = *(const h16x8*)&As[r * 64 + ((slot ^ (r & 7)) << 3)];
      }
#pragma unroll
      for (int n = 0; n < 4; ++n) {
        int r = cb2 + n * 16;
        bfr[n] = *(const h16x8*)&Bs[r * 64 + ((slot ^ (r & 7)) << 3)];
      }
#pragma unroll
      for (int m = 0; m < 4; ++m)
#pragma unroll
        for (int n = 0; n < 4; ++n)
          acc[m][n] = __builtin_amdgcn_mfma_f32_16x16x32_f16(af[m], bfr[n], acc[m][n], 0, 0, 0);
    }
    __syncthreads();
  }

#pragma unroll
  for (int m = 0; m < 4; ++m) {
    int row0 = brow + wr * 64 + m * 16 + ((l >> 4) << 2);
#pragma unroll
    for (int n = 0; n < 4; ++n) {
      int col = bcol + wc * 64 + n * 16 + (l & 15);
      float bv = bias ? bias[col] : 0.f;
#pragma unroll
      for (int i = 0; i < 4; ++i) {
        int row = row0 + i;
        float v = acc[m][n][i] + bv;
        if (RELU) v = fmaxf(v, 0.f);
        if (OUT_MODE == 1) {
          ((h16*)C)[(size_t)row * N + col] = (h16)v;
        } else if (OUT_MODE == 2) {
          int rr = ((row & 15) << 7) + (row >> 4);
          ((float*)C)[(size_t)rr * N + col] = v;
        } else {
          ((float*)C)[(size_t)row * N + col] = v;
        }
      }
    }
  }
}

// ---------- fp16 MFMA GEMM 128Mx256N for the logit projection ----------
__global__ __launch_bounds__(256, 1) void gemm_bt256(
    const h16* __restrict__ A, const h16* __restrict__ B,
    const float* __restrict__ bias, float* __restrict__ C,
    int M, int N, int K)
{
  __shared__ h16 As[128 * 64];
  __shared__ h16 Bs[256 * 64];
  int tid = threadIdx.x;
  int l = tid & 63, wv = tid >> 6;
  int wr = wv >> 1, wc = wv & 1;

  int work = blockIdx.x;
  int q = gridDim.x >> 3; work = (work & 7) * q + (work >> 3);
  int nMp = M >> 7;
  int brow = (work % nMp) << 7;
  int bcol = (work / nMp) << 8;

  f32x4 acc[4][8];
#pragma unroll
  for (int m = 0; m < 4; ++m)
#pragma unroll
    for (int n = 0; n < 8; ++n) acc[m][n] = (f32x4){0.f, 0.f, 0.f, 0.f};

  int nkt = K >> 6;
  for (int kt = 0; kt < nkt; ++kt) {
    const h16* Ag = A + (size_t)brow * K + kt * 64;
    const h16* Bg = B + (size_t)bcol * K + kt * 64;
#pragma unroll
    for (int c = tid; c < 3072; c += 256) {
      int isB = (c >= 1024);
      int cc = isB ? (c - 1024) : c;
      int row = cc >> 3, slot = cc & 7;
      const h16* src = (isB ? Bg : Ag) + (size_t)row * K + slot * 8;
      uint4 v = *(const uint4*)src;
      h16* dst = (isB ? Bs : As) + row * 64 + ((slot ^ (row & 7)) << 3);
      *(uint4*)dst = v;
    }
    __syncthreads();
#pragma unroll
    for (int kk = 0; kk < 2; ++kk) {
      h16x8 af[4], bfr[8];
      int rb = wr * 64 + (l & 15);
      int cb2 = wc * 128 + (l & 15);
      int slot = kk * 4 + (l >> 4);
#pragma unroll
      for (int m = 0; m < 4; ++m) {
        int r = rb + m * 16;
        af[m] = *(const h16x8*)&As[r * 64 + ((slot ^ (r & 7)) << 3)];
      }
#pragma unroll
      for (int n = 0; n < 8; ++n) {
        int r = cb2 + n * 16;
        bfr[n] = *(const h16x8*)&Bs[r * 64 + ((slot ^ (r & 7)) << 3)];
      }
#pragma unroll
      for (int m = 0; m < 4; ++m)
#pragma unroll
        for (int n = 0; n < 8; ++n)
          acc[m][n] = __builtin_amdgcn_mfma_f32_16x16x32_f16(af[m], bfr[n], acc[m][n], 0, 0, 0);
    }
    __syncthreads();
  }

#pragma unroll
  for (int m = 0; m < 4; ++m) {
    int row0 = brow + wr * 64 + m * 16 + ((l >> 4) << 2);
#pragma unroll
    for (int n = 0; n < 8; ++n) {
      int col = bcol + wc * 128 + n * 16 + (l & 15);
      float bv = bias[col];
#pragma unroll
      for (int i = 0; i < 4; ++i) {
        int row = row0 + i;
        int rr = ((row & 15) << 7) + (row >> 4);   // b*128 + s
        C[(size_t)rr * N + col] = acc[m][n][i] + bv;
      }
    }
  }
}

// ---------- sentinel helpers: 0xFFFF halfword = "not yet written" (fp16 -NaN) ----------
__device__ __forceinline__ bool bad64(u64 x) {
  u64 m = ~x;   // bad halfword (0xFFFF) -> zero halfword in m
  return ((m - 0x0001000100010001ull) & ~m & 0x8000800080008000ull) != 0ull;
}
__device__ __forceinline__ u64 aload(const u64* p) {
  return __hip_atomic_load(p, __ATOMIC_RELAXED, __HIP_MEMORY_SCOPE_AGENT);
}

#define ISSUE8(va, p, t0)                                            \
  _Pragma("unroll")                                                  \
  for (int t = 0; t < 8; ++t) {                                      \
    (va)[2 * t]     = aload((p) + ((t0) + t) * 8);                   \
    (va)[2 * t + 1] = aload((p) + ((t0) + t) * 8 + 1);               \
  }

#define CLEAN8(va, p, t0)                                            \
  for (;;) {                                                         \
    bool dirty = false;                                              \
    _Pragma("unroll")                                                \
    for (int t = 0; t < 8; ++t) {                                    \
      if (bad64((va)[2 * t]))     { (va)[2 * t]     = aload((p) + ((t0) + t) * 8);     dirty = true; } \
      if (bad64((va)[2 * t + 1])) { (va)[2 * t + 1] = aload((p) + ((t0) + t) * 8 + 1); dirty = true; } \
    }                                                                \
    if (!dirty) break;                                               \
  }                                                                  \
  asm volatile("" ::: "memory");

#define MFMA8(a0, a1, va, Bf, t0)                                    \
  _Pragma("unroll")                                                  \
  for (int t = 0; t < 8; t += 2) {                                   \
    union { u64 u[2]; h16x8 v; } A0, A1;                             \
    A0.u[0] = (va)[2 * t];     A0.u[1] = (va)[2 * t + 1];            \
    A1.u[0] = (va)[2 * t + 2]; A1.u[1] = (va)[2 * t + 3];            \
    a0 = __builtin_amdgcn_mfma_f32_16x16x32_f16(A0.v, (Bf)[(t0) + t],     a0, 0, 0, 0); \
    a1 = __builtin_amdgcn_mfma_f32_16x16x32_f16(A1.v, (Bf)[(t0) + t + 1], a1, 0, 0, 0); \
  }

// ---------- persistent dataflow GRU recurrence: data-as-flag, no barriers/flags ----------
// 96 blocks x 384 threads (6 waves). Rings pre-filled with 0xFFFF; producers store real
// h16 (relaxed agent u16); consumers acquire A-fragments via relaxed agent u64 atomic
// loads with sentinel retry (4-group pipelined). One __syncthreads per step (gate exch),
// exch parity-double-buffered so no trailing barrier.
__global__ __launch_bounds__(384, 2) void gru_df(
    const float* __restrict__ gi0,
    const float* __restrict__ hidden,
    const h16* __restrict__ hinit16,
    const h16* __restrict__ whh0, const float* __restrict__ bhh0,
    const h16* __restrict__ wih1, const float* __restrict__ bih1,
    const h16* __restrict__ whh1, const float* __restrict__ bhh1,
    h16* __restrict__ h0ring,       // [128][16][1024]
    h16* __restrict__ H1A)          // [128][16][1024]
{
  __shared__ float exch[2][5][256];
  int bid = blockIdx.x;
  int tid = threadIdx.x;
  int w = tid >> 6, l = tid & 63;
  int li = l & 15;
  int ko = (l >> 4) << 3;            // k-offset within 32-wide tile (h16 units)
  int b0 = (l >> 4) << 2;            // first batch row of this lane's acc
  int u64b = ((li << 10) + ko) >> 2; // lane base in u64 units within a 16x1024 plane

  if (bid < NL0) {
    // ================= layer 0 =================
    int gate = w >> 1, ch = w & 1;
    int j = bid * 32 + ch * 16 + li;
    h16x8 Bf[32];
    {
      const h16* wp = whh0 + ((size_t)((gate << 10) + j) << 10) + ko;
#pragma unroll
      for (int t = 0; t < 32; ++t) Bf[t] = *(const h16x8*)(wp + t * 32);
    }
    float bR = 0.f, bZ = 0.f, bN = 0.f;
    float hprev[4];
    if (gate == 2) {
      bR = bhh0[j]; bZ = bhh0[1024 + j]; bN = bhh0[2048 + j];
#pragma unroll
      for (int i = 0; i < 4; ++i) hprev[i] = hidden[((b0 + i) << 10) + j];
    }

    for (int s = 0; s < Sn; ++s) {
      float gr[4], gz[4], gn[4];
      if (gate == 2) {
        const float* gb = gi0 + ((size_t)s << 4) * H3;
#pragma unroll
        for (int i = 0; i < 4; ++i) {
          const float* g = gb + (size_t)(b0 + i) * H3 + j;
          gr[i] = g[0]; gz[i] = g[1024]; gn[i] = g[2048];
        }
      }
      const h16* hsrc = (s == 0) ? hinit16 : h0ring + (((size_t)(s - 1)) << 14);
      const u64* p = (const u64*)hsrc + u64b;
      u64 va[2][16];
      f32x4 a0 = (f32x4){0.f, 0.f, 0.f, 0.f};
      f32x4 a1 = (f32x4){0.f, 0.f, 0.f, 0.f};
      ISSUE8(va[0], p, 0)
      ISSUE8(va[1], p, 8)
      CLEAN8(va[0], p, 0)
      MFMA8(a0, a1, va[0], Bf, 0)
      ISSUE8(va[0], p, 16)
      CLEAN8(va[1], p, 8)
      MFMA8(a0, a1, va[1], Bf, 8)
      ISSUE8(va[1], p, 24)
      CLEAN8(va[0], p, 16)
      MFMA8(a0, a1, va[0], Bf, 16)
      CLEAN8(va[1], p, 24)
      MFMA8(a0, a1, va[1], Bf, 24)
      f32x4 acc = a0 + a1;
      int pb = s & 1;
      if (w < 4) {
#pragma unroll
        for (int i = 0; i < 4; ++i) exch[pb][w][((b0 + i) << 4) + li] = acc[i];
      }
      __syncthreads();
      if (gate == 2) {
#pragma unroll
        for (int i = 0; i < 4; ++i) {
          int e = ((b0 + i) << 4) + li;
          float r = 1.f / (1.f + expf(-(exch[pb][ch][e] + bR + gr[i])));
          float z = 1.f / (1.f + expf(-(exch[pb][2 + ch][e] + bZ + gz[i])));
          float n = tanhf(gn[i] + r * (acc[i] + bN));
          float out = (1.f - z) * n + z * hprev[i];
          hprev[i] = out;
          h16 hv = (h16)out; unsigned short us; __builtin_memcpy(&us, &hv, 2);
          __hip_atomic_store((unsigned short*)h0ring + (((size_t)s) << 14) + ((b0 + i) << 10) + j,
                             us, __ATOMIC_RELAXED, __HIP_MEMORY_SCOPE_AGENT);
        }
      }
    }
  } else {
    // ================= layer 1 =================
    int bl = bid - NL0;
    int j = (bl << 4) + li;
    int isHH = (w >= 3);
    int gate = isHH ? (w - 3) : w;
    h16x8 Bf[32];
    {
      const h16* wsrc = isHH ? whh1 : wih1;
      const h16* wp = wsrc + ((size_t)((gate << 10) + j) << 10) + ko;
#pragma unroll
      for (int t = 0; t < 32; ++t) Bf[t] = *(const h16x8*)(wp + t * 32);
    }
    float bIR = 0.f, bIZ = 0.f, bIN = 0.f, bHR = 0.f, bHZ = 0.f, bHN = 0.f;
    float hprev[4];
    if (w == 5) {
      bIR = bih1[j]; bIZ = bih1[1024 + j]; bIN = bih1[2048 + j];
      bHR = bhh1[j]; bHZ = bhh1[1024 + j]; bHN = bhh1[2048 + j];
#pragma unroll
      for (int i = 0; i < 4; ++i) hprev[i] = hidden[16384 + ((b0 + i) << 10) + j];
    }

    for (int s = 1; s <= Sn; ++s) {
      const h16* hsrc = isHH
          ? ((s == 1) ? hinit16 + 16384 : H1A + (((size_t)(s - 2)) << 14))
          : (h0ring + (((size_t)(s - 1)) << 14));
      const u64* p = (const u64*)hsrc + u64b;
      u64 va[2][16];
      f32x4 a0 = (f32x4){0.f, 0.f, 0.f, 0.f};
      f32x4 a1 = (f32x4){0.f, 0.f, 0.f, 0.f};
      ISSUE8(va[0], p, 0)
      ISSUE8(va[1], p, 8)
      CLEAN8(va[0], p, 0)
      MFMA8(a0, a1, va[0], Bf, 0)
      ISSUE8(va[0], p, 16)
      CLEAN8(va[1], p, 8)
      MFMA8(a0, a1, va[1], Bf, 8)
      ISSUE8(va[1], p, 24)
      CLEAN8(va[0], p, 16)
      MFMA8(a0, a1, va[0], Bf, 16)
      CLEAN8(va[1], p, 24)
      MFMA8(a0, a1, va[1], Bf, 24)
      f32x4 acc = a0 + a1;
      int pb = s & 1;
      if (w < 5) {
#pragma unroll
        for (int i = 0; i < 4; ++i) exch[pb][w][((b0 + i) << 4) + li] = acc[i];
      }
      __syncthreads();
      if (w == 5) {
#pragma unroll
        for (int i = 0; i < 4; ++i) {
          int e = ((b0 + i) << 4) + li;
          float r = 1.f / (1.f + expf(-(exch[pb][0][e] + bIR + exch[pb][3][e] + bHR)));
          float z = 1.f / (1.f + expf(-(exch[pb][1][e] + bIZ + exch[pb][4][e] + bHZ)));
          float n = tanhf(exch[pb][2][e] + bIN + r * (acc[i] + bHN));
          float out = (1.f - z) * n + z * hprev[i];
          hprev[i] = out;
          h16 hv = (h16)out; unsigned short us; __builtin_memcpy(&us, &hv, 2);
          __hip_atomic_store((unsigned short*)H1A + (((size_t)(s - 1)) << 14) + ((b0 + i) << 10) + j,
                             us, __ATOMIC_RELAXED, __HIP_MEMORY_SCOPE_AGENT);
        }
      }
    }
  }
}

extern "C" void kernel_launch(void* const* d_in, const int* in_sizes, int n_in,
                              void* d_out, int out_size, void* d_ws, size_t ws_size,
                              hipStream_t stream) {
  const float* hidden = (const float*)d_in[0];
  const int*   trg    = (const int*)d_in[1];
  const float* emb    = (const float*)d_in[2];
  const float* w_ih0  = (const float*)d_in[3];
  const float* w_hh0  = (const float*)d_in[4];
  const float* b_ih0  = (const float*)d_in[5];
  const float* b_hh0  = (const float*)d_in[6];
  const float* w_ih1  = (const float*)d_in[7];
  const float* w_hh1  = (const float*)d_in[8];
  const float* b_ih1  = (const float*)d_in[9];
  const float* b_hh1  = (const float*)d_in[10];
  const float* w1     = (const float*)d_in[11];
  const float* b1     = (const float*)d_in[12];
  const float* w2     = (const float*)d_in[13];
  const float* b2     = (const float*)d_in[14];
  const float* b_gen  = (const float*)d_in[15];

  char* ws = (char*)d_ws;
  size_t off = 0;
  float* GI0    = (float*)(ws + off); off += (size_t)Sn * Bn * H3 * 4;      // 25.2 MB
  h16* Xh       = (h16*)(ws + off);   off += (size_t)Sn * Bn * En * 2;
  h16* embH     = (h16*)(ws + off);   off += (size_t)Vn * En * 2;
  h16* wih0H    = (h16*)(ws + off);   off += (size_t)H3 * En * 2;
  h16* w1H      = (h16*)(ws + off);   off += (size_t)Hn * Hn * 2;
  h16* w2H      = (h16*)(ws + off);   off += (size_t)En * Hn * 2;
  h16* whh0H    = (h16*)(ws + off);   off += (size_t)H3 * Hn * 2;
  h16* wih1H    = (h16*)(ws + off);   off += (size_t)H3 * Hn * 2;
  h16* whh1H    = (h16*)(ws + off);   off += (size_t)H3 * Hn * 2;
  h16* H1A      = (h16*)(ws + off);   off += (size_t)Sn * Bn * Hn * 2;      // 4.2 MB
  h16* h0ring   = (h16*)(ws + off);   off += (size_t)Sn * Bn * Hn * 2;      // 4.2 MB
  h16* hinit16  = (h16*)(ws + off);   off += (size_t)2 * Bn * Hn * 2;
  // Tb/Ub alias GI0 (dead after the recurrence)
  h16* Tb = (h16*)GI0;
  h16* Ub = (h16*)((char*)GI0 + (8u << 20));

  // fp16 copies of all operands (one fused launch) + embedding gather
  cvt_all_k<<<28320, 256, 0, stream>>>(emb, w_ih0, w1, w2, w_hh0, w_ih1, w_hh1, hidden,
                                       embH, wih0H, w1H, w2H, whh0H, wih1H, whh1H, hinit16);
  embed_k<<<Sn * Bn, 128, 0, stream>>>(trg, emb, Xh);

  // GI0 = X @ w_ih0^T + b_ih0 (hoisted out of the recurrence)
  gemm_bt<0, false, true><<<384, 256, 0, stream>>>(Xh, wih0H, b_ih0, GI0, Sn * Bn, H3, En);

  // sentinel-fill both rings (H1A and h0ring are adjacent: one memset), then dataflow GRU
  (void)hipMemsetAsync(H1A, 0xFF, (size_t)2 * Sn * Bn * Hn * 2, stream);
  gru_df<<<NL0 + NL1, 384, 0, stream>>>(GI0, hidden, hinit16,
                                        whh0H, b_hh0, wih1H, b_ih1, whh1H, b_hh1,
                                        h0ring, H1A);

  // output head, batched over all 2048 rows
  gemm_bt<1, true,  true><<<128,  256, 0, stream>>>(H1A, w1H, b1, Tb, Sn * Bn, Hn, Hn);
  gemm_bt<1, false, true><<<64,   256, 0, stream>>>(Tb, w2H, b2, Ub, Sn * Bn, En, Hn);
  gemm_bt256<<<2000, 256, 0, stream>>>(Ub, embH, b_gen, (float*)d_out, Sn * Bn, Vn, En);
}

// Round 10
// 2693.284 us; speedup vs baseline: 1.3658x; 1.3658x over previous
//
#include <hip/hip_runtime.h>
#include <math.h>

// Problem dims
#define Sn 128
#define Bn 16
#define Hn 1024
#define En 512
#define Vn 32000
#define H3 3072

typedef _Float16 h16;
typedef __attribute__((ext_vector_type(4))) _Float16 h16x4;
typedef __attribute__((ext_vector_type(8))) _Float16 h16x8;
typedef __attribute__((ext_vector_type(4))) float f32x4;

// ---------- fused f32 -> fp16 convert for ALL operands (one launch) ----------
#define Q_EMB   4096000
#define Q_WIH0  (Q_EMB + 393216)
#define Q_W1    (Q_WIH0 + 262144)
#define Q_W2    (Q_W1 + 131072)
#define Q_WHH0  (Q_W2 + 786432)
#define Q_WIH1  (Q_WHH0 + 786432)
#define Q_WHH1  (Q_WIH1 + 786432)
#define Q_HID   (Q_WHH1 + 8192)
__global__ __launch_bounds__(256) void cvt_all_k(
    const float* __restrict__ emb, const float* __restrict__ wih0,
    const float* __restrict__ w1, const float* __restrict__ w2,
    const float* __restrict__ whh0, const float* __restrict__ wih1,
    const float* __restrict__ whh1, const float* __restrict__ hid,
    h16* __restrict__ E, h16* __restrict__ A, h16* __restrict__ B1,
    h16* __restrict__ B2, h16* __restrict__ D0, h16* __restrict__ D1,
    h16* __restrict__ D2, h16* __restrict__ HD)
{
  int i = blockIdx.x * 256 + threadIdx.x;
  const float* s; h16* d; int o;
  if      (i < Q_EMB)  { s = emb;  d = E;  o = i; }
  else if (i < Q_WIH0) { s = wih0; d = A;  o = i - Q_EMB; }
  else if (i < Q_W1)   { s = w1;   d = B1; o = i - Q_WIH0; }
  else if (i < Q_W2)   { s = w2;   d = B2; o = i - Q_W1; }
  else if (i < Q_WHH0) { s = whh0; d = D0; o = i - Q_W2; }
  else if (i < Q_WIH1) { s = wih1; d = D1; o = i - Q_WHH0; }
  else if (i < Q_WHH1) { s = whh1; d = D2; o = i - Q_WIH1; }
  else                 { s = hid;  d = HD; o = i - Q_WHH1; }
  float4 v = *(const float4*)(s + (size_t)o * 4);
  h16x4 ov = { (h16)v.x, (h16)v.y, (h16)v.z, (h16)v.w };
  *(h16x4*)(d + (size_t)o * 4) = ov;
}

// ---------- embedding gather -> fp16 X, time-major rows t = s*Bn + b ----------
__global__ void embed_k(const int* __restrict__ trg, const float* __restrict__ emb,
                        h16* __restrict__ Xh) {
  int t = blockIdx.x;
  int s = t >> 4, b = t & 15;
  int tok = trg[b * Sn + s];
  const float* src = emb + (size_t)tok * En;
  int e = threadIdx.x * 4;
  float4 v = *(const float4*)(src + e);
  h16x4 o = { (h16)v.x, (h16)v.y, (h16)v.z, (h16)v.w };
  *(h16x4*)(Xh + (size_t)t * En + e) = o;
}

// ---------- fp16 MFMA GEMM 128x128: C(M,N) = A(M,K) @ B(N,K)^T + bias ----------
template<int OUT_MODE, bool RELU, bool SWZ>
__global__ __launch_bounds__(256) void gemm_bt(
    const h16* __restrict__ A, const h16* __restrict__ B,
    const float* __restrict__ bias, void* __restrict__ C,
    int M, int N, int K)
{
  __shared__ h16 As[128 * 64];
  __shared__ h16 Bs[128 * 64];
  int tid = threadIdx.x;
  int l = tid & 63, wv = tid >> 6;
  int wr = wv >> 1, wc = wv & 1;

  int work = blockIdx.x;
  if (SWZ) { int q = gridDim.x >> 3; work = (work & 7) * q + (work >> 3); }
  int nMp = M >> 7;
  int brow = (work % nMp) << 7;
  int bcol = (work / nMp) << 7;

  f32x4 acc[4][4];
#pragma unroll
  for (int m = 0; m < 4; ++m)
#pragma unroll
    for (int n = 0; n < 4; ++n) acc[m][n] = (f32x4){0.f, 0.f, 0.f, 0.f};

  int nkt = K >> 6;
  for (int kt = 0; kt < nkt; ++kt) {
    const h16* Ag = A + (size_t)brow * K + kt * 64;
    const h16* Bg = B + (size_t)bcol * K + kt * 64;
#pragma unroll
    for (int c = tid; c < 2048; c += 256) {
      int half = c >> 10;
      int cc = c & 1023;
      int row = cc >> 3, slot = cc & 7;
      const h16* src = (half ? Bg : Ag) + (size_t)row * K + slot * 8;
      uint4 v = *(const uint4*)src;
      h16* dst = (half ? Bs : As) + row * 64 + ((slot ^ (row & 7)) << 3);
      *(uint4*)dst = v;
    }
    __syncthreads();
#pragma unroll
    for (int kk = 0; kk < 2; ++kk) {
      h16x8 af[4], bfr[4];
      int rb = wr * 64 + (l & 15);
      int cb2 = wc * 64 + (l & 15);
      int slot = kk * 4 + (l >> 4);
#pragma unroll
      for (int m = 0; m < 4; ++m) {
        int r = rb + m * 16;
        af[m] = *(const h16x8*)&As[r * 64 + ((slot ^ (r & 7)) << 3)];
      }
#pragma unroll
      for (int n = 0; n < 4; ++n) {
        int r = cb2 + n * 16;
        bfr[n] = *(const h16x8*)&Bs[r * 64 + ((slot ^ (r & 7)) << 3)];
      }
#pragma unroll
      for (int m = 0; m < 4; ++m)
#pragma unroll
        for (int n = 0; n < 4; ++n)
          acc[m][n] = __builtin_amdgcn_mfma_f32_16x16x32_f16(af[m], bfr[n], acc[m][n], 0, 0, 0);
    }
    __syncthreads();
  }

#pragma unroll
  for (int m = 0; m < 4; ++m) {
    int row0 = brow + wr * 64 + m * 16 + ((l >> 4) << 2);
#pragma unroll
    for (int n = 0; n < 4; ++n) {
      int col = bcol + wc * 64 + n * 16 + (l & 15);
      float bv = bias ? bias[col] : 0.f;
#pragma unroll
      for (int i = 0; i < 4; ++i) {
        int row = row0 + i;
        float v = acc[m][n][i] + bv;
        if (RELU) v = fmaxf(v, 0.f);
        if (OUT_MODE == 1) {
          ((h16*)C)[(size_t)row * N + col] = (h16)v;
        } else if (OUT_MODE == 2) {
          int rr = ((row & 15) << 7) + (row >> 4);
          ((float*)C)[(size_t)rr * N + col] = v;
        } else {
          ((float*)C)[(size_t)row * N + col] = v;
        }
      }
    }
  }
}

// ---------- fp16 MFMA GEMM 128Mx256N for the logit projection ----------
__global__ __launch_bounds__(256, 1) void gemm_bt256(
    const h16* __restrict__ A, const h16* __restrict__ B,
    const float* __restrict__ bias, float* __restrict__ C,
    int M, int N, int K)
{
  __shared__ h16 As[128 * 64];
  __shared__ h16 Bs[256 * 64];
  int tid = threadIdx.x;
  int l = tid & 63, wv = tid >> 6;
  int wr = wv >> 1, wc = wv & 1;

  int work = blockIdx.x;
  int q = gridDim.x >> 3; work = (work & 7) * q + (work >> 3);
  int nMp = M >> 7;
  int brow = (work % nMp) << 7;
  int bcol = (work / nMp) << 8;

  f32x4 acc[4][8];
#pragma unroll
  for (int m = 0; m < 4; ++m)
#pragma unroll
    for (int n = 0; n < 8; ++n) acc[m][n] = (f32x4){0.f, 0.f, 0.f, 0.f};

  int nkt = K >> 6;
  for (int kt = 0; kt < nkt; ++kt) {
    const h16* Ag = A + (size_t)brow * K + kt * 64;
    const h16* Bg = B + (size_t)bcol * K + kt * 64;
#pragma unroll
    for (int c = tid; c < 3072; c += 256) {
      int isB = (c >= 1024);
      int cc = isB ? (c - 1024) : c;
      int row = cc >> 3, slot = cc & 7;
      const h16* src = (isB ? Bg : Ag) + (size_t)row * K + slot * 8;
      uint4 v = *(const uint4*)src;
      h16* dst = (isB ? Bs : As) + row * 64 + ((slot ^ (row & 7)) << 3);
      *(uint4*)dst = v;
    }
    __syncthreads();
#pragma unroll
    for (int kk = 0; kk < 2; ++kk) {
      h16x8 af[4], bfr[8];
      int rb = wr * 64 + (l & 15);
      int cb2 = wc * 128 + (l & 15);
      int slot = kk * 4 + (l >> 4);
#pragma unroll
      for (int m = 0; m < 4; ++m) {
        int r = rb + m * 16;
        af[m] = *(const h16x8*)&As[r * 64 + ((slot ^ (r & 7)) << 3)];
      }
#pragma unroll
      for (int n = 0; n < 8; ++n) {
        int r = cb2 + n * 16;
        bfr[n] = *(const h16x8*)&Bs[r * 64 + ((slot ^ (r & 7)) << 3)];
      }
#pragma unroll
      for (int m = 0; m < 4; ++m)
#pragma unroll
        for (int n = 0; n < 8; ++n)
          acc[m][n] = __builtin_amdgcn_mfma_f32_16x16x32_f16(af[m], bfr[n], acc[m][n], 0, 0, 0);
    }
    __syncthreads();
  }

#pragma unroll
  for (int m = 0; m < 4; ++m) {
    int row0 = brow + wr * 64 + m * 16 + ((l >> 4) << 2);
#pragma unroll
    for (int n = 0; n < 8; ++n) {
      int col = bcol + wc * 128 + n * 16 + (l & 15);
      float bv = bias[col];
#pragma unroll
      for (int i = 0; i < 4; ++i) {
        int row = row0 + i;
        int rr = ((row & 15) << 7) + (row >> 4);   // b*128 + s
        C[(size_t)rr * N + col] = acc[m][n][i] + bv;
      }
    }
  }
}

// ---------- load-group / MFMA-chain macros (static indices only) ----------
#define LOADG(dst, base, t0)                                           \
  _Pragma("unroll")                                                    \
  for (int t = 0; t < 8; ++t) (dst)[t] = *(const h16x8*)((base) + ((t0) + t) * 32);

#define CHAING(a0, a1, src, Bw, t0)                                    \
  _Pragma("unroll")                                                    \
  for (int t = 0; t < 8; t += 2) {                                     \
    a0 = __builtin_amdgcn_mfma_f32_16x16x32_f16((src)[t],     (Bw)[(t0) + t],     a0, 0, 0, 0); \
    a1 = __builtin_amdgcn_mfma_f32_16x16x32_f16((src)[t + 1], (Bw)[(t0) + t + 1], a1, 0, 0, 0); \
  }

// ---------- persistent dataflow GRU, XCD-pinned, flag-based ----------
// Grid 256 x 384 (6 waves). Roles by bid%8 (blocks round-robin across the 8 XCDs):
//   residue 0            -> layer 0 (32 blocks, XCD0): waves = 3 gates x 2 col-halves,
//                           gate-2 waves do the update for their 16 cols.
//   residues 1,2         -> layer 1 (64 blocks, XCD1/2): waves 0-2 ih, 3-5 hh; wave 5 updates.
//   other residues       -> exit immediately.
// Weights pinned in VGPRs (opaque asm). Handoff: ring u16 stores -> s_waitcnt vmcnt(0)
// -> packed flag store; consumers: every wave polls 64 packed flags (one coalesced load),
// then plain vectorized A-loads. One __syncthreads per step (parity-double-buffered exch).
__global__ __launch_bounds__(384) void gru_pin(
    const float* __restrict__ gi0,
    const float* __restrict__ hidden,
    const h16* __restrict__ hinit16,
    const h16* __restrict__ whh0, const float* __restrict__ bhh0,
    const h16* __restrict__ wih1, const float* __restrict__ bih1,
    const h16* __restrict__ whh1, const float* __restrict__ bhh1,
    h16* __restrict__ h0ring,       // [128][16][1024]
    h16* __restrict__ H1A,          // [128][16][1024]
    int* __restrict__ flags)        // fL0[64] @ 0, fL1[64] @ +1024 (ints, packed)
{
  __shared__ float exch[2][5][256];
  int bid = blockIdx.x;
  int res = bid & 7;
  if (res > 2) return;
  int tid = threadIdx.x;
  int w = tid >> 6, l = tid & 63;
  int li = l & 15;
  int ko = (l >> 4) << 3;
  int b0 = (l >> 4) << 2;

  __threadfence();                   // one-time replay-staleness guard

  int* fL0 = flags;
  int* fL1 = flags + 1024;

  if (res == 0) {
    // ================= layer 0 (XCD0) =================
    int blk = bid >> 3;              // 0..31
    int gate = w >> 1, ch = w & 1;
    int j = blk * 32 + ch * 16 + li;
    h16x8 Bf[32];
    {
      const h16* wp = whh0 + ((size_t)((gate << 10) + j) << 10) + ko;
#pragma unroll
      for (int t = 0; t < 32; ++t) Bf[t] = *(const h16x8*)(wp + t * 32);
#pragma unroll
      for (int t = 0; t < 32; ++t) asm volatile("" : "+v"(Bf[t]));   // pin: no remat
    }
    float bR = 0.f, bZ = 0.f, bN = 0.f;
    float hprev[4];
    if (gate == 2) {
      bR = bhh0[j]; bZ = bhh0[1024 + j]; bN = bhh0[2048 + j];
#pragma unroll
      for (int i = 0; i < 4; ++i) hprev[i] = hidden[((b0 + i) << 10) + j];
    }

    for (int s = 0; s < Sn; ++s) {
      float gr[4], gz[4], gn[4];
      if (gate == 2) {                // prefetch gi BEFORE poll (hides under wait)
        const float* gb = gi0 + ((size_t)s << 4) * H3;
#pragma unroll
        for (int i = 0; i < 4; ++i) {
          const float* g = gb + (size_t)(b0 + i) * H3 + j;
          gr[i] = g[0]; gz[i] = g[1024]; gn[i] = g[2048];
        }
      }
      asm volatile("" ::: "memory");
      if (s > 0) {
        while (__hip_atomic_load(&fL0[l], __ATOMIC_RELAXED, __HIP_MEMORY_SCOPE_AGENT) < s) {}
        asm volatile("" ::: "memory");
      }
      const h16* hsrc = (s == 0) ? hinit16 : h0ring + (((size_t)(s - 1)) << 14);
      const h16* Ap = hsrc + (li << 10) + ko;
      h16x8 va[8], vb[8];
      f32x4 a0 = (f32x4){0.f, 0.f, 0.f, 0.f};
      f32x4 a1 = (f32x4){0.f, 0.f, 0.f, 0.f};
      LOADG(va, Ap, 0)  LOADG(vb, Ap, 8)
      CHAING(a0, a1, va, Bf, 0)
      LOADG(va, Ap, 16)
      CHAING(a0, a1, vb, Bf, 8)
      LOADG(vb, Ap, 24)
      CHAING(a0, a1, va, Bf, 16)
      CHAING(a0, a1, vb, Bf, 24)
      f32x4 acc = a0 + a1;
      int pb = s & 1;
      if (w < 4) {
#pragma unroll
        for (int i = 0; i < 4; ++i) exch[pb][w][((b0 + i) << 4) + li] = acc[i];
      }
      __syncthreads();
      if (gate == 2) {
#pragma unroll
        for (int i = 0; i < 4; ++i) {
          int e = ((b0 + i) << 4) + li;
          float r = 1.f / (1.f + expf(-(exch[pb][ch][e] + bR + gr[i])));
          float z = 1.f / (1.f + expf(-(exch[pb][2 + ch][e] + bZ + gz[i])));
          float n = tanhf(gn[i] + r * (acc[i] + bN));
          float out = (1.f - z) * n + z * hprev[i];
          hprev[i] = out;
          h16 hv = (h16)out; unsigned short us; __builtin_memcpy(&us, &hv, 2);
          __hip_atomic_store((unsigned short*)h0ring + (((size_t)s) << 14) + ((b0 + i) << 10) + j,
                             us, __ATOMIC_RELAXED, __HIP_MEMORY_SCOPE_AGENT);
        }
        asm volatile("s_waitcnt vmcnt(0)" ::: "memory");
        if (l == 0)
          __hip_atomic_store(&fL0[blk * 2 + ch], s + 1, __ATOMIC_RELAXED, __HIP_MEMORY_SCOPE_AGENT);
      }
    }
  } else {
    // ================= layer 1 (XCD1/2) =================
    int idx = ((bid >> 3) << 1) + (res - 1);   // 0..63
    int j = (idx << 4) + li;
    int isHH = (w >= 3);
    int gate = isHH ? (w - 3) : w;
    h16x8 Bf[32];
    {
      const h16* wsrc = isHH ? whh1 : wih1;
      const h16* wp = wsrc + ((size_t)((gate << 10) + j) << 10) + ko;
#pragma unroll
      for (int t = 0; t < 32; ++t) Bf[t] = *(const h16x8*)(wp + t * 32);
#pragma unroll
      for (int t = 0; t < 32; ++t) asm volatile("" : "+v"(Bf[t]));   // pin: no remat
    }
    float bIR = 0.f, bIZ = 0.f, bIN = 0.f, bHR = 0.f, bHZ = 0.f, bHN = 0.f;
    float hprev[4];
    if (w == 5) {
      bIR = bih1[j]; bIZ = bih1[1024 + j]; bIN = bih1[2048 + j];
      bHR = bhh1[j]; bHZ = bhh1[1024 + j]; bHN = bhh1[2048 + j];
#pragma unroll
      for (int i = 0; i < 4; ++i) hprev[i] = hidden[16384 + ((b0 + i) << 10) + j];
    }

    for (int s = 1; s <= Sn; ++s) {
      asm volatile("" ::: "memory");
      if (!isHH) {
        while (__hip_atomic_load(&fL0[l], __ATOMIC_RELAXED, __HIP_MEMORY_SCOPE_AGENT) < s) {}
        asm volatile("" ::: "memory");
      } else if (s >= 2) {
        while (__hip_atomic_load(&fL1[l], __ATOMIC_RELAXED, __HIP_MEMORY_SCOPE_AGENT) < s - 1) {}
        asm volatile("" ::: "memory");
      }
      const h16* hsrc = isHH
          ? ((s == 1) ? hinit16 + 16384 : H1A + (((size_t)(s - 2)) << 14))
          : (h0ring + (((size_t)(s - 1)) << 14));
      const h16* Ap = hsrc + (li << 10) + ko;
      h16x8 va[8], vb[8];
      f32x4 a0 = (f32x4){0.f, 0.f, 0.f, 0.f};
      f32x4 a1 = (f32x4){0.f, 0.f, 0.f, 0.f};
      LOADG(va, Ap, 0)  LOADG(vb, Ap, 8)
      CHAING(a0, a1, va, Bf, 0)
      LOADG(va, Ap, 16)
      CHAING(a0, a1, vb, Bf, 8)
      LOADG(vb, Ap, 24)
      CHAING(a0, a1, va, Bf, 16)
      CHAING(a0, a1, vb, Bf, 24)
      f32x4 acc = a0 + a1;
      int pb = s & 1;
      if (w < 5) {
#pragma unroll
        for (int i = 0; i < 4; ++i) exch[pb][w][((b0 + i) << 4) + li] = acc[i];
      }
      __syncthreads();
      if (w == 5) {
#pragma unroll
        for (int i = 0; i < 4; ++i) {
          int e = ((b0 + i) << 4) + li;
          float r = 1.f / (1.f + expf(-(exch[pb][0][e] + bIR + exch[pb][3][e] + bHR)));
          float z = 1.f / (1.f + expf(-(exch[pb][1][e] + bIZ + exch[pb][4][e] + bHZ)));
          float n = tanhf(exch[pb][2][e] + bIN + r * (acc[i] + bHN));
          float out = (1.f - z) * n + z * hprev[i];
          hprev[i] = out;
          h16 hv = (h16)out; unsigned short us; __builtin_memcpy(&us, &hv, 2);
          __hip_atomic_store((unsigned short*)H1A + (((size_t)(s - 1)) << 14) + ((b0 + i) << 10) + j,
                             us, __ATOMIC_RELAXED, __HIP_MEMORY_SCOPE_AGENT);
        }
        asm volatile("s_waitcnt vmcnt(0)" ::: "memory");
        if (l == 0)
          __hip_atomic_store(&fL1[idx], s, __ATOMIC_RELAXED, __HIP_MEMORY_SCOPE_AGENT);
      }
    }
  }
}

extern "C" void kernel_launch(void* const* d_in, const int* in_sizes, int n_in,
                              void* d_out, int out_size, void* d_ws, size_t ws_size,
                              hipStream_t stream) {
  const float* hidden = (const float*)d_in[0];
  const int*   trg    = (const int*)d_in[1];
  const float* emb    = (const float*)d_in[2];
  const float* w_ih0  = (const float*)d_in[3];
  const float* w_hh0  = (const float*)d_in[4];
  const float* b_ih0  = (const float*)d_in[5];
  const float* b_hh0  = (const float*)d_in[6];
  const float* w_ih1  = (const float*)d_in[7];
  const float* w_hh1  = (const float*)d_in[8];
  const float* b_ih1  = (const float*)d_in[9];
  const float* b_hh1  = (const float*)d_in[10];
  const float* w1     = (const float*)d_in[11];
  const float* b1     = (const float*)d_in[12];
  const float* w2     = (const float*)d_in[13];
  const float* b2     = (const float*)d_in[14];
  const float* b_gen  = (const float*)d_in[15];

  char* ws = (char*)d_ws;
  size_t off = 0;
  float* GI0    = (float*)(ws + off); off += (size_t)Sn * Bn * H3 * 4;      // 25.2 MB
  h16* Xh       = (h16*)(ws + off);   off += (size_t)Sn * Bn * En * 2;
  h16* embH     = (h16*)(ws + off);   off += (size_t)Vn * En * 2;
  h16* wih0H    = (h16*)(ws + off);   off += (size_t)H3 * En * 2;
  h16* w1H      = (h16*)(ws + off);   off += (size_t)Hn * Hn * 2;
  h16* w2H      = (h16*)(ws + off);   off += (size_t)En * Hn * 2;
  h16* whh0H    = (h16*)(ws + off);   off += (size_t)H3 * Hn * 2;
  h16* wih1H    = (h16*)(ws + off);   off += (size_t)H3 * Hn * 2;
  h16* whh1H    = (h16*)(ws + off);   off += (size_t)H3 * Hn * 2;
  h16* H1A      = (h16*)(ws + off);   off += (size_t)Sn * Bn * Hn * 2;      // 4.2 MB
  h16* h0ring   = (h16*)(ws + off);   off += (size_t)Sn * Bn * Hn * 2;      // 4.2 MB
  h16* hinit16  = (h16*)(ws + off);   off += (size_t)2 * Bn * Hn * 2;
  int* flags    = (int*)(ws + off);   off += 32768;
  // Tb/Ub alias GI0 (dead after the recurrence)
  h16* Tb = (h16*)GI0;
  h16* Ub = (h16*)((char*)GI0 + (8u << 20));

  // fp16 copies of all operands (one fused launch) + embedding gather
  cvt_all_k<<<28320, 256, 0, stream>>>(emb, w_ih0, w1, w2, w_hh0, w_ih1, w_hh1, hidden,
                                       embH, wih0H, w1H, w2H, whh0H, wih1H, whh1H, hinit16);
  embed_k<<<Sn * Bn, 128, 0, stream>>>(trg, emb, Xh);

  // GI0 = X @ w_ih0^T + b_ih0 (hoisted out of the recurrence)
  gemm_bt<0, false, true><<<384, 256, 0, stream>>>(Xh, wih0H, b_ih0, GI0, Sn * Bn, H3, En);

  // persistent dataflow recurrence: XCD-pinned roles, packed flags
  (void)hipMemsetAsync(flags, 0, 32768, stream);
  gru_pin<<<256, 384, 0, stream>>>(GI0, hidden, hinit16,
                                   whh0H, b_hh0, wih1H, b_ih1, whh1H, b_hh1,
                                   h0ring, H1A, flags);

  // output head, batched over all 2048 rows
  gemm_bt<1, true,  true><<<128,  256, 0, stream>>>(H1A, w1H, b1, Tb, Sn * Bn, Hn, Hn);
  gemm_bt<1, false, true><<<64,   256, 0, stream>>>(Tb, w2H, b2, Ub, Sn * Bn, En, Hn);
  gemm_bt256<<<2000, 256, 0, stream>>>(Ub, embH, b_gen, (float*)d_out, Sn * Bn, Vn, En);
}

// Round 11
// 1636.697 us; speedup vs baseline: 2.2476x; 1.6456x over previous
//
#include <hip/hip_runtime.h>
#include <math.h>

// Problem dims
#define Sn 128
#define Bn 16
#define Hn 1024
#define En 512
#define Vn 32000
#define H3 3072
#define NL0 32
#define NL1 64

typedef _Float16 h16;
typedef __attribute__((ext_vector_type(4))) _Float16 h16x4;
typedef __attribute__((ext_vector_type(8))) _Float16 h16x8;
typedef __attribute__((ext_vector_type(4))) float f32x4;

// ---------- fused f32 -> fp16 convert for ALL operands (one launch) ----------
#define Q_EMB   4096000
#define Q_WIH0  (Q_EMB + 393216)
#define Q_W1    (Q_WIH0 + 262144)
#define Q_W2    (Q_W1 + 131072)
#define Q_WHH0  (Q_W2 + 786432)
#define Q_WIH1  (Q_WHH0 + 786432)
#define Q_WHH1  (Q_WIH1 + 786432)
#define Q_HID   (Q_WHH1 + 8192)
__global__ __launch_bounds__(256) void cvt_all_k(
    const float* __restrict__ emb, const float* __restrict__ wih0,
    const float* __restrict__ w1, const float* __restrict__ w2,
    const float* __restrict__ whh0, const float* __restrict__ wih1,
    const float* __restrict__ whh1, const float* __restrict__ hid,
    h16* __restrict__ E, h16* __restrict__ A, h16* __restrict__ B1,
    h16* __restrict__ B2, h16* __restrict__ D0, h16* __restrict__ D1,
    h16* __restrict__ D2, h16* __restrict__ HD)
{
  int i = blockIdx.x * 256 + threadIdx.x;
  const float* s; h16* d; int o;
  if      (i < Q_EMB)  { s = emb;  d = E;  o = i; }
  else if (i < Q_WIH0) { s = wih0; d = A;  o = i - Q_EMB; }
  else if (i < Q_W1)   { s = w1;   d = B1; o = i - Q_WIH0; }
  else if (i < Q_W2)   { s = w2;   d = B2; o = i - Q_W1; }
  else if (i < Q_WHH0) { s = whh0; d = D0; o = i - Q_W2; }
  else if (i < Q_WIH1) { s = wih1; d = D1; o = i - Q_WHH0; }
  else if (i < Q_WHH1) { s = whh1; d = D2; o = i - Q_WIH1; }
  else                 { s = hid;  d = HD; o = i - Q_WHH1; }
  float4 v = *(const float4*)(s + (size_t)o * 4);
  h16x4 ov = { (h16)v.x, (h16)v.y, (h16)v.z, (h16)v.w };
  *(h16x4*)(d + (size_t)o * 4) = ov;
}

// ---------- embedding gather -> fp16 X, time-major rows t = s*Bn + b ----------
__global__ void embed_k(const int* __restrict__ trg, const float* __restrict__ emb,
                        h16* __restrict__ Xh) {
  int t = blockIdx.x;
  int s = t >> 4, b = t & 15;
  int tok = trg[b * Sn + s];
  const float* src = emb + (size_t)tok * En;
  int e = threadIdx.x * 4;
  float4 v = *(const float4*)(src + e);
  h16x4 o = { (h16)v.x, (h16)v.y, (h16)v.z, (h16)v.w };
  *(h16x4*)(Xh + (size_t)t * En + e) = o;
}

// ---------- fp16 MFMA GEMM 128x128: C(M,N) = A(M,K) @ B(N,K)^T + bias ----------
template<int OUT_MODE, bool RELU, bool SWZ>
__global__ __launch_bounds__(256) void gemm_bt(
    const h16* __restrict__ A, const h16* __restrict__ B,
    const float* __restrict__ bias, void* __restrict__ C,
    int M, int N, int K)
{
  __shared__ h16 As[128 * 64];
  __shared__ h16 Bs[128 * 64];
  int tid = threadIdx.x;
  int l = tid & 63, wv = tid >> 6;
  int wr = wv >> 1, wc = wv & 1;

  int work = blockIdx.x;
  if (SWZ) { int q = gridDim.x >> 3; work = (work & 7) * q + (work >> 3); }
  int nMp = M >> 7;
  int brow = (work % nMp) << 7;
  int bcol = (work / nMp) << 7;

  f32x4 acc[4][4];
#pragma unroll
  for (int m = 0; m < 4; ++m)
#pragma unroll
    for (int n = 0; n < 4; ++n) acc[m][n] = (f32x4){0.f, 0.f, 0.f, 0.f};

  int nkt = K >> 6;
  for (int kt = 0; kt < nkt; ++kt) {
    const h16* Ag = A + (size_t)brow * K + kt * 64;
    const h16* Bg = B + (size_t)bcol * K + kt * 64;
#pragma unroll
    for (int c = tid; c < 2048; c += 256) {
      int half = c >> 10;
      int cc = c & 1023;
      int row = cc >> 3, slot = cc & 7;
      const h16* src = (half ? Bg : Ag) + (size_t)row * K + slot * 8;
      uint4 v = *(const uint4*)src;
      h16* dst = (half ? Bs : As) + row * 64 + ((slot ^ (row & 7)) << 3);
      *(uint4*)dst = v;
    }
    __syncthreads();
#pragma unroll
    for (int kk = 0; kk < 2; ++kk) {
      h16x8 af[4], bfr[4];
      int rb = wr * 64 + (l & 15);
      int cb2 = wc * 64 + (l & 15);
      int slot = kk * 4 + (l >> 4);
#pragma unroll
      for (int m = 0; m < 4; ++m) {
        int r = rb + m * 16;
        af[m] = *(const h16x8*)&As[r * 64 + ((slot ^ (r & 7)) << 3)];
      }
#pragma unroll
      for (int n = 0; n < 4; ++n) {
        int r = cb2 + n * 16;
        bfr[n] = *(const h16x8*)&Bs[r * 64 + ((slot ^ (r & 7)) << 3)];
      }
#pragma unroll
      for (int m = 0; m < 4; ++m)
#pragma unroll
        for (int n = 0; n < 4; ++n)
          acc[m][n] = __builtin_amdgcn_mfma_f32_16x16x32_f16(af[m], bfr[n], acc[m][n], 0, 0, 0);
    }
    __syncthreads();
  }

#pragma unroll
  for (int m = 0; m < 4; ++m) {
    int row0 = brow + wr * 64 + m * 16 + ((l >> 4) << 2);
#pragma unroll
    for (int n = 0; n < 4; ++n) {
      int col = bcol + wc * 64 + n * 16 + (l & 15);
      float bv = bias ? bias[col] : 0.f;
#pragma unroll
      for (int i = 0; i < 4; ++i) {
        int row = row0 + i;
        float v = acc[m][n][i] + bv;
        if (RELU) v = fmaxf(v, 0.f);
        if (OUT_MODE == 1) {
          ((h16*)C)[(size_t)row * N + col] = (h16)v;
        } else if (OUT_MODE == 2) {
          int rr = ((row & 15) << 7) + (row >> 4);
          ((float*)C)[(size_t)rr * N + col] = v;
        } else {
          ((float*)C)[(size_t)row * N + col] = v;
        }
      }
    }
  }
}

// ---------- fp16 MFMA GEMM 128Mx256N for the logit projection ----------
__global__ __launch_bounds__(256, 1) void gemm_bt256(
    const h16* __restrict__ A, const h16* __restrict__ B,
    const float* __restrict__ bias, float* __restrict__ C,
    int M, int N, int K)
{
  __shared__ h16 As[128 * 64];
  __shared__ h16 Bs[256 * 64];
  int tid = threadIdx.x;
  int l = tid & 63, wv = tid >> 6;
  int wr = wv >> 1, wc = wv & 1;

  int work = blockIdx.x;
  int q = gridDim.x >> 3; work = (work & 7) * q + (work >> 3);
  int nMp = M >> 7;
  int brow = (work % nMp) << 7;
  int bcol = (work / nMp) << 8;

  f32x4 acc[4][8];
#pragma unroll
  for (int m = 0; m < 4; ++m)
#pragma unroll
    for (int n = 0; n < 8; ++n) acc[m][n] = (f32x4){0.f, 0.f, 0.f, 0.f};

  int nkt = K >> 6;
  for (int kt = 0; kt < nkt; ++kt) {
    const h16* Ag = A + (size_t)brow * K + kt * 64;
    const h16* Bg = B + (size_t)bcol * K + kt * 64;
#pragma unroll
    for (int c = tid; c < 3072; c += 256) {
      int isB = (c >= 1024);
      int cc = isB ? (c - 1024) : c;
      int row = cc >> 3, slot = cc & 7;
      const h16* src = (isB ? Bg : Ag) + (size_t)row * K + slot * 8;
      uint4 v = *(const uint4*)src;
      h16* dst = (isB ? Bs : As) + row * 64 + ((slot ^ (row & 7)) << 3);
      *(uint4*)dst = v;
    }
    __syncthreads();
#pragma unroll
    for (int kk = 0; kk < 2; ++kk) {
      h16x8 af[4], bfr[8];
      int rb = wr * 64 + (l & 15);
      int cb2 = wc * 128 + (l & 15);
      int slot = kk * 4 + (l >> 4);
#pragma unroll
      for (int m = 0; m < 4; ++m) {
        int r = rb + m * 16;
        af[m] = *(const h16x8*)&As[r * 64 + ((slot ^ (r & 7)) << 3)];
      }
#pragma unroll
      for (int n = 0; n < 8; ++n) {
        int r = cb2 + n * 16;
        bfr[n] = *(const h16x8*)&Bs[r * 64 + ((slot ^ (r & 7)) << 3)];
      }
#pragma unroll
      for (int m = 0; m < 4; ++m)
#pragma unroll
        for (int n = 0; n < 8; ++n)
          acc[m][n] = __builtin_amdgcn_mfma_f32_16x16x32_f16(af[m], bfr[n], acc[m][n], 0, 0, 0);
    }
    __syncthreads();
  }

#pragma unroll
  for (int m = 0; m < 4; ++m) {
    int row0 = brow + wr * 64 + m * 16 + ((l >> 4) << 2);
#pragma unroll
    for (int n = 0; n < 8; ++n) {
      int col = bcol + wc * 128 + n * 16 + (l & 15);
      float bv = bias[col];
#pragma unroll
      for (int i = 0; i < 4; ++i) {
        int row = row0 + i;
        int rr = ((row & 15) << 7) + (row >> 4);   // b*128 + s
        C[(size_t)rr * N + col] = acc[m][n][i] + bv;
      }
    }
  }
}

// ---------- load-group / MFMA-chain macros (static indices only) ----------
#define LOAD4(dst, base, t0)                                           \
  _Pragma("unroll")                                                    \
  for (int t = 0; t < 4; ++t) (dst)[t] = *(const h16x8*)((base) + ((t0) + t) * 32);

#define CHAIN4(a0, a1, src, Bw, t0)                                    \
  _Pragma("unroll")                                                    \
  for (int t = 0; t < 4; t += 2) {                                     \
    a0 = __builtin_amdgcn_mfma_f32_16x16x32_f16((src)[t],     (Bw)[(t0) + t],     a0, 0, 0, 0); \
    a1 = __builtin_amdgcn_mfma_f32_16x16x32_f16((src)[t + 1], (Bw)[(t0) + t + 1], a1, 0, 0, 0); \
  }

#define PIPE32(a0, a1, Ap, Bf)                                         \
  {                                                                    \
    h16x8 va[4], vb[4];                                                \
    LOAD4(va, Ap, 0)  LOAD4(vb, Ap, 4)                                 \
    CHAIN4(a0, a1, va, Bf, 0)   LOAD4(va, Ap, 8)                       \
    CHAIN4(a0, a1, vb, Bf, 4)   LOAD4(vb, Ap, 12)                      \
    CHAIN4(a0, a1, va, Bf, 8)   LOAD4(va, Ap, 16)                      \
    CHAIN4(a0, a1, vb, Bf, 12)  LOAD4(vb, Ap, 20)                      \
    CHAIN4(a0, a1, va, Bf, 16)  LOAD4(va, Ap, 24)                      \
    CHAIN4(a0, a1, vb, Bf, 20)  LOAD4(vb, Ap, 28)                      \
    CHAIN4(a0, a1, va, Bf, 24)                                         \
    CHAIN4(a0, a1, vb, Bf, 28)                                         \
  }

// force the 32 weight fragments to stay register-resident across the step loop
#define PINW(Bf)                                                       \
  _Pragma("unroll")                                                    \
  for (int t = 0; t < 32; ++t) asm volatile("" : "+v"((Bf)[t]));

// ---------- persistent dataflow GRU: round-8 structure + pinned weights ----------
// 96 blocks x 384 threads (6 waves).
//   blocks [0,32): layer0, 32 cols: waves = 3 gates x 2 col-halves; gate-2 waves update.
//   blocks [32,96): layer1, 16 cols: waves 0-2 ih, 3-5 hh; wave 5 updates.
// Weights truly pinned in VGPRs via in-loop opaque asm (~215 VGPR, cap 256).
// Sync: single-poller wave + __syncthreads broadcast (2 barriers/step);
// update waves self-publish: ring u16 stores -> s_waitcnt vmcnt(0) -> flag store.
__global__ __launch_bounds__(384, 2) void gru_pin2(
    const float* __restrict__ gi0,
    const float* __restrict__ hidden,
    const h16* __restrict__ hinit16,
    const h16* __restrict__ whh0, const float* __restrict__ bhh0,
    const h16* __restrict__ wih1, const float* __restrict__ bih1,
    const h16* __restrict__ whh1, const float* __restrict__ bhh1,
    h16* __restrict__ h0ring,       // [128][16][1024]
    h16* __restrict__ H1A,          // [128][16][1024]
    int* __restrict__ flags)        // fL0[64] @ stride 4 ints; fL1[64] @ +512 ints
{
  __shared__ float exch[5][256];
  int bid = blockIdx.x;
  int tid = threadIdx.x;
  int w = tid >> 6, l = tid & 63;
  int li = l & 15;
  int ko = (l >> 4) << 3;
  int b0 = (l >> 4) << 2;

  __threadfence();                   // one-time replay-staleness guard

  int* fL0 = flags;
  int* fL1 = flags + 512;

  if (bid < NL0) {
    // ================= layer 0 =================
    int blk = bid;
    int gate = w >> 1, ch = w & 1;
    int j = blk * 32 + ch * 16 + li;
    h16x8 Bf[32];
    {
      const h16* wp = whh0 + ((size_t)((gate << 10) + j) << 10) + ko;
#pragma unroll
      for (int t = 0; t < 32; ++t) Bf[t] = *(const h16x8*)(wp + t * 32);
    }
    float bR = 0.f, bZ = 0.f, bN = 0.f;
    float hprev[4];
    if (gate == 2) {
      bR = bhh0[j]; bZ = bhh0[1024 + j]; bN = bhh0[2048 + j];
#pragma unroll
      for (int i = 0; i < 4; ++i) hprev[i] = hidden[((b0 + i) << 10) + j];
    }

    for (int s = 0; s < Sn; ++s) {
      PINW(Bf)
      // gi prefetch BEFORE poll (latency hides under the wait)
      float gr[4], gz[4], gn[4];
      if (gate == 2) {
        const float* gb = gi0 + ((size_t)s << 4) * H3;
#pragma unroll
        for (int i = 0; i < 4; ++i) {
          const float* g = gb + (size_t)(b0 + i) * H3 + j;
          gr[i] = g[0]; gz[i] = g[1024]; gn[i] = g[2048];
        }
      }
      if (s > 0) {
        if (w == 0)
          while (__hip_atomic_load(&fL0[l << 2], __ATOMIC_RELAXED, __HIP_MEMORY_SCOPE_AGENT) < s) {}
        __syncthreads();
        asm volatile("" ::: "memory");
      }
      const h16* hsrc = (s == 0) ? hinit16 : h0ring + (((size_t)(s - 1)) << 14);
      const h16* Ap = hsrc + (li << 10) + ko;
      f32x4 a0 = (f32x4){0.f, 0.f, 0.f, 0.f};
      f32x4 a1 = (f32x4){0.f, 0.f, 0.f, 0.f};
      PIPE32(a0, a1, Ap, Bf)
      f32x4 acc = a0 + a1;
      if (w < 4) {
#pragma unroll
        for (int i = 0; i < 4; ++i) exch[w][((b0 + i) << 4) + li] = acc[i];
      }
      __syncthreads();
      if (gate == 2) {
#pragma unroll
        for (int i = 0; i < 4; ++i) {
          int e = ((b0 + i) << 4) + li;
          float r = 1.f / (1.f + expf(-(exch[ch][e] + bR + gr[i])));
          float z = 1.f / (1.f + expf(-(exch[2 + ch][e] + bZ + gz[i])));
          float n = tanhf(gn[i] + r * (acc[i] + bN));
          float out = (1.f - z) * n + z * hprev[i];
          hprev[i] = out;
          h16 hv = (h16)out; unsigned short us; __builtin_memcpy(&us, &hv, 2);
          __hip_atomic_store((unsigned short*)h0ring + (((size_t)s) << 14) + ((b0 + i) << 10) + j,
                             us, __ATOMIC_RELAXED, __HIP_MEMORY_SCOPE_AGENT);
        }
        asm volatile("s_waitcnt vmcnt(0)" ::: "memory");
        if (l == 0)
          __hip_atomic_store(&fL0[(blk * 2 + ch) << 2], s + 1,
                             __ATOMIC_RELAXED, __HIP_MEMORY_SCOPE_AGENT);
      }
    }
  } else {
    // ================= layer 1 =================
    int idx = bid - NL0;             // 0..63
    int j = (idx << 4) + li;
    int isHH = (w >= 3);
    int gate = isHH ? (w - 3) : w;
    h16x8 Bf[32];
    {
      const h16* wsrc = isHH ? whh1 : wih1;
      const h16* wp = wsrc + ((size_t)((gate << 10) + j) << 10) + ko;
#pragma unroll
      for (int t = 0; t < 32; ++t) Bf[t] = *(const h16x8*)(wp + t * 32);
    }
    float bIR = 0.f, bIZ = 0.f, bIN = 0.f, bHR = 0.f, bHZ = 0.f, bHN = 0.f;
    float hprev[4];
    if (w == 5) {
      bIR = bih1[j]; bIZ = bih1[1024 + j]; bIN = bih1[2048 + j];
      bHR = bhh1[j]; bHZ = bhh1[1024 + j]; bHN = bhh1[2048 + j];
#pragma unroll
      for (int i = 0; i < 4; ++i) hprev[i] = hidden[16384 + ((b0 + i) << 10) + j];
    }

    for (int s = 1; s <= Sn; ++s) {
      PINW(Bf)
      if (w == 0) {
        while (__hip_atomic_load(&fL0[l << 2], __ATOMIC_RELAXED, __HIP_MEMORY_SCOPE_AGENT) < s) {}
      } else if (w == 1 && s >= 2) {
        while (__hip_atomic_load(&fL1[l << 2], __ATOMIC_RELAXED, __HIP_MEMORY_SCOPE_AGENT) < s - 1) {}
      }
      __syncthreads();
      asm volatile("" ::: "memory");
      const h16* hsrc = isHH
          ? ((s == 1) ? hinit16 + 16384 : H1A + (((size_t)(s - 2)) << 14))
          : (h0ring + (((size_t)(s - 1)) << 14));
      const h16* Ap = hsrc + (li << 10) + ko;
      f32x4 a0 = (f32x4){0.f, 0.f, 0.f, 0.f};
      f32x4 a1 = (f32x4){0.f, 0.f, 0.f, 0.f};
      PIPE32(a0, a1, Ap, Bf)
      f32x4 acc = a0 + a1;
      if (w < 5) {
#pragma unroll
        for (int i = 0; i < 4; ++i) exch[w][((b0 + i) << 4) + li] = acc[i];
      }
      __syncthreads();
      if (w == 5) {
#pragma unroll
        for (int i = 0; i < 4; ++i) {
          int e = ((b0 + i) << 4) + li;
          float r = 1.f / (1.f + expf(-(exch[0][e] + bIR + exch[3][e] + bHR)));
          float z = 1.f / (1.f + expf(-(exch[1][e] + bIZ + exch[4][e] + bHZ)));
          float n = tanhf(exch[2][e] + bIN + r * (acc[i] + bHN));
          float out = (1.f - z) * n + z * hprev[i];
          hprev[i] = out;
          h16 hv = (h16)out; unsigned short us; __builtin_memcpy(&us, &hv, 2);
          __hip_atomic_store((unsigned short*)H1A + (((size_t)(s - 1)) << 14) + ((b0 + i) << 10) + j,
                             us, __ATOMIC_RELAXED, __HIP_MEMORY_SCOPE_AGENT);
        }
        asm volatile("s_waitcnt vmcnt(0)" ::: "memory");
        if (l == 0)
          __hip_atomic_store(&fL1[idx << 2], s, __ATOMIC_RELAXED, __HIP_MEMORY_SCOPE_AGENT);
      }
    }
  }
}

extern "C" void kernel_launch(void* const* d_in, const int* in_sizes, int n_in,
                              void* d_out, int out_size, void* d_ws, size_t ws_size,
                              hipStream_t stream) {
  const float* hidden = (const float*)d_in[0];
  const int*   trg    = (const int*)d_in[1];
  const float* emb    = (const float*)d_in[2];
  const float* w_ih0  = (const float*)d_in[3];
  const float* w_hh0  = (const float*)d_in[4];
  const float* b_ih0  = (const float*)d_in[5];
  const float* b_hh0  = (const float*)d_in[6];
  const float* w_ih1  = (const float*)d_in[7];
  const float* w_hh1  = (const float*)d_in[8];
  const float* b_ih1  = (const float*)d_in[9];
  const float* b_hh1  = (const float*)d_in[10];
  const float* w1     = (const float*)d_in[11];
  const float* b1     = (const float*)d_in[12];
  const float* w2     = (const float*)d_in[13];
  const float* b2     = (const float*)d_in[14];
  const float* b_gen  = (const float*)d_in[15];

  char* ws = (char*)d_ws;
  size_t off = 0;
  float* GI0    = (float*)(ws + off); off += (size_t)Sn * Bn * H3 * 4;      // 25.2 MB
  h16* Xh       = (h16*)(ws + off);   off += (size_t)Sn * Bn * En * 2;
  h16* embH     = (h16*)(ws + off);   off += (size_t)Vn * En * 2;
  h16* wih0H    = (h16*)(ws + off);   off += (size_t)H3 * En * 2;
  h16* w1H      = (h16*)(ws + off);   off += (size_t)Hn * Hn * 2;
  h16* w2H      = (h16*)(ws + off);   off += (size_t)En * Hn * 2;
  h16* whh0H    = (h16*)(ws + off);   off += (size_t)H3 * Hn * 2;
  h16* wih1H    = (h16*)(ws + off);   off += (size_t)H3 * Hn * 2;
  h16* whh1H    = (h16*)(ws + off);   off += (size_t)H3 * Hn * 2;
  h16* H1A      = (h16*)(ws + off);   off += (size_t)Sn * Bn * Hn * 2;      // 4.2 MB
  h16* h0ring   = (h16*)(ws + off);   off += (size_t)Sn * Bn * Hn * 2;      // 4.2 MB
  h16* hinit16  = (h16*)(ws + off);   off += (size_t)2 * Bn * Hn * 2;
  int* flags    = (int*)(ws + off);   off += 8192;
  // Tb/Ub alias GI0 (dead after the recurrence)
  h16* Tb = (h16*)GI0;
  h16* Ub = (h16*)((char*)GI0 + (8u << 20));

  // fp16 copies of all operands (one fused launch) + embedding gather
  cvt_all_k<<<28320, 256, 0, stream>>>(emb, w_ih0, w1, w2, w_hh0, w_ih1, w_hh1, hidden,
                                       embH, wih0H, w1H, w2H, whh0H, wih1H, whh1H, hinit16);
  embed_k<<<Sn * Bn, 128, 0, stream>>>(trg, emb, Xh);

  // GI0 = X @ w_ih0^T + b_ih0 (hoisted out of the recurrence)
  gemm_bt<0, false, true><<<384, 256, 0, stream>>>(Xh, wih0H, b_ih0, GI0, Sn * Bn, H3, En);

  // persistent dataflow recurrence (round-8 structure, pinned weights)
  (void)hipMemsetAsync(flags, 0, 8192, stream);
  gru_pin2<<<NL0 + NL1, 384, 0, stream>>>(GI0, hidden, hinit16,
                                          whh0H, b_hh0, wih1H, b_ih1, whh1H, b_hh1,
                                          h0ring, H1A, flags);

  // output head, batched over all 2048 rows
  gemm_bt<1, true,  true><<<128,  256, 0, stream>>>(H1A, w1H, b1, Tb, Sn * Bn, Hn, Hn);
  gemm_bt<1, false, true><<<64,   256, 0, stream>>>(Tb, w2H, b2, Ub, Sn * Bn, En, Hn);
  gemm_bt256<<<2000, 256, 0, stream>>>(Ub, embH, b_gen, (float*)d_out, Sn * Bn, Vn, En);
}